// Round 7
// baseline (251.328 us; speedup 1.0000x reference)
//
#include <hip/hip_runtime.h>

#define HID 1024
#define SEQ 2048
#define NB 4
#define BS 8192  // NB*SEQ

typedef __attribute__((ext_vector_type(8))) short short8;
typedef __attribute__((ext_vector_type(8))) unsigned short ushort8;
typedef __attribute__((ext_vector_type(4))) float f32x4;

__device__ __forceinline__ float bf2f(unsigned short u) {
  unsigned int x = ((unsigned int)u) << 16;
  return __builtin_bit_cast(float, x);
}
__device__ __forceinline__ unsigned short f2bf(float f) {
  unsigned int x = __builtin_bit_cast(unsigned int, f);
  x = x + 0x7fffu + ((x >> 16) & 1u);
  return (unsigned short)(x >> 16);
}

#define GLOAD16(g, l)                                                          \
  __builtin_amdgcn_global_load_lds(                                            \
      (const __attribute__((address_space(1))) unsigned int*)(g),              \
      (__attribute__((address_space(3))) unsigned int*)(l), 16, 0, 0)

template <int N>
__device__ __forceinline__ void vmwait() {
  asm volatile("s_waitcnt vmcnt(%0)" ::"i"(N) : "memory");
}

// ---------------- fp32 -> bf16 cast, 8 elems/thread ----------------
__global__ void cast_f32_to_bf16(const float* __restrict__ in,
                                 unsigned short* __restrict__ out, int n) {
  int i = (blockIdx.x * 256 + threadIdx.x) * 8;
  if (i >= n) return;
  f32x4 a = *(const f32x4*)(in + i);
  f32x4 b = *(const f32x4*)(in + i + 4);
  ushort8 o;
  o[0] = f2bf(a[0]); o[1] = f2bf(a[1]); o[2] = f2bf(a[2]); o[3] = f2bf(a[3]);
  o[4] = f2bf(b[0]); o[5] = f2bf(b[1]); o[6] = f2bf(b[2]); o[7] = f2bf(b[3]);
  *(ushort8*)(out + i) = o;
}

// ------------- 1024x1024 fp32 -> bf16 transposed cast -------------
__global__ __launch_bounds__(256) void transpose_cast(
    const float* __restrict__ in, unsigned short* __restrict__ out) {
  __shared__ float t[32][33];
  const int bx = blockIdx.x * 32, by = blockIdx.y * 32;
  const int tx = threadIdx.x & 31, ty = threadIdx.x >> 5;  // 32 x 8
#pragma unroll
  for (int i = 0; i < 4; ++i)
    t[ty + i * 8][tx] = in[(by + ty + i * 8) * 1024 + bx + tx];
  __syncthreads();
#pragma unroll
  for (int i = 0; i < 4; ++i)
    out[(bx + ty + i * 8) * 1024 + by + tx] = f2bf(t[tx][ty + i * 8]);
}

// ------------- b'[h] = bo[h] + sum_k Wo[h,k] * bv[k] -------------
__global__ __launch_bounds__(256) void bias_fuse(const float* __restrict__ Wo,
                                                 const float* __restrict__ bv,
                                                 const float* __restrict__ bo,
                                                 float* __restrict__ bp) {
  const int row = blockIdx.x * 4 + (threadIdx.x >> 6);
  const int lane = threadIdx.x & 63;
  float s = 0.f;
  for (int k = lane; k < 1024; k += 64) s += Wo[row * 1024 + k] * bv[k];
#pragma unroll
  for (int off = 32; off >= 1; off >>= 1) s += __shfl_xor(s, off, 64);
  if (lane == 0) bp[row] = s + bo[row];
}

// ============ 128 x BN deep-pipelined NT GEMM (BK=32, 3 buffers) ===========
// C[m,n] = alpha * sum_k A[m,k]*B[n,k] (+bias). 256 thr = 4 waves (2x2).
// 3 LDS buffers, prefetch depth 2: stage(t+2) issued at iter t, waited at
// iter t+2 -> ~2 full iterations (500+ cy) of memory latency hidden.
// One raw s_barrier per iteration + counted vmcnt (never 0 mid-loop).
// LDS XOR swizzle: phys_slot(16B) = logical_slot ^ (row bits 1-2); this puts
// each 8-lane phase of a ds_read_b128 on all 8 bank-quads (conflict-free),
// since quad = 4*(row&1) + slot (16B = 4 banks = +1 quad). Applied to the
// GLOBAL source column (gload_lds dest stays linear) and to ds_read offsets.
// BIAS_MODE: 0 none, 1 bias[col], 3 col<1024?bias:bias2.
// EPI: 0 plain, 1 exp(v)+rowsum->Srow atomics, 2 scale by 1/Srow.
template <int BN, int OUT_F32, int BIAS_MODE, int EPI>
__global__ __launch_bounds__(256, (BN == 128 ? 3 : 4)) void gemm_p3(
    const unsigned short* __restrict__ A, const unsigned short* __restrict__ B,
    void* __restrict__ Cv, const float* __restrict__ bias,
    const float* __restrict__ bias2, float* __restrict__ Srow, int K, int lda,
    int ldb, int ldc, long long bsA, long long bsB, long long bsC,
    float alpha) {
  static_assert(BN == 128 || BN == 64, "BN");
  constexpr int NF = BN / 32;             // B frags per wave (4 or 2)
  constexpr int LPS = (BN == 128) ? 4 : 3;  // gloads per stage

  __shared__ unsigned short lA[3][128 * 32];  // 24 KB
  __shared__ unsigned short lB[3][BN * 32];   // 24 or 12 KB

  const int tid = threadIdx.x;
  const int lane = tid & 63, wid = tid >> 6;
  const int fr = lane & 15, fq = lane >> 4;
  const int wm = wid >> 1, wn = wid & 1;

  // XCD-aware chunked swizzle on flattened (y,x); all grids have nwg%8==0.
  const int nx = gridDim.x;
  const int nwg = nx * gridDim.y;
  int f = blockIdx.y * nx + blockIdx.x;
  f = (f & 7) * (nwg >> 3) + (f >> 3);
  const int bx = f % nx, by = f / nx;
  const int bz = blockIdx.z;

  const unsigned short* Ag = A + bz * bsA + (long long)by * 128 * lda;
  const unsigned short* Bg = B + bz * bsB + (long long)bx * BN * ldb;
  const int NT = K >> 5;

  // Staging: LDS dest linear (wave-uniform base + lane*16B). Global source
  // column pre-swizzled: phys slot (tid&3) holds logical slot
  // (tid&3)^((row>>1)&3), row = tid>>2.
  const int srow = tid >> 2;
  const int scol = 8 * ((tid & 3) ^ ((tid >> 3) & 3));
  const int lbase = wid * 512;  // ushorts, wave-uniform

  auto stage = [&](int t) {
    const int b3 = t - (t / 3) * 3;
    unsigned short* dA = &lA[b3][lbase];
    GLOAD16(Ag + (long long)srow * lda + t * 32 + scol, dA);
    GLOAD16(Ag + (long long)(64 + srow) * lda + t * 32 + scol, dA + 2048);
    unsigned short* dB = &lB[b3][lbase];
    GLOAD16(Bg + (long long)srow * ldb + t * 32 + scol, dB);
    if (BN == 128)
      GLOAD16(Bg + (long long)(64 + srow) * ldb + t * 32 + scol, dB + 2048);
  };

  // ds_read offsets: XOR the 16B-slot with row bits 1-2 (= fr bits 1-2).
  const int xm = ((fr >> 1) & 3) << 3;  // ushort-unit mask (bits 3-4)

  f32x4 acc[4][NF] = {};

  stage(0);
  stage(1);

  for (int t = 0; t < NT; ++t) {
    // Wait for stage(t) (issued 2 iters ago); keep stage(t+1) in flight.
    if (t + 1 < NT) vmwait<LPS>(); else vmwait<0>();
    __builtin_amdgcn_s_barrier();       // publishes buf t; closes reads of t-1
    __builtin_amdgcn_sched_barrier(0);  // keep ds_reads below the barrier
    if (t + 2 < NT) stage(t + 2);       // overwrites buf (t-1)%3 - WAR safe
    const int b3 = t - (t / 3) * 3;
    const unsigned short* pa = lA[b3];
    const unsigned short* pb = lB[b3];
    short8 av[4], bw[NF];
#pragma unroll
    for (int i = 0; i < 4; ++i)
      av[i] = *(const short8*)(pa +
                               (((wm * 64 + i * 16 + fr) * 32 + fq * 8) ^ xm));
#pragma unroll
    for (int n = 0; n < NF; ++n)
      bw[n] = *(const short8*)(pb + (((wn * (BN / 2) + n * 16 + fr) * 32 +
                                      fq * 8) ^ xm));
#pragma unroll
    for (int i = 0; i < 4; ++i)
#pragma unroll
      for (int n = 0; n < NF; ++n)
        acc[i][n] = __builtin_amdgcn_mfma_f32_16x16x32_bf16(av[i], bw[n],
                                                            acc[i][n], 0, 0, 0);
  }

  // Epilogue. C/D frag layout: col = 16*frag + fr, row = fq*4 + j.
  if (EPI == 1) __syncthreads();  // sredf aliases lA; close last-tile reads
  const long long cb0 = (long long)bz * bsC;
  float* sredf = (float*)lA;  // [128][2] row-sum scratch (EPI==1)
#pragma unroll
  for (int i = 0; i < 4; ++i)
#pragma unroll
    for (int j = 0; j < 4; ++j) {
      const int row = wm * 64 + i * 16 + fq * 4 + j;
      float inv = 1.0f;
      if (EPI == 2) inv = 1.0f / Srow[(long long)bz * SEQ + by * 128 + row];
      float rps = 0.0f;
#pragma unroll
      for (int n = 0; n < NF; ++n) {
        const int col = bx * BN + wn * (BN / 2) + n * 16 + fr;
        float v = acc[i][n][j] * alpha;
        if (EPI == 1) { v = __expf(v); rps += v; }
        if (EPI == 2) v *= inv;
        if (BIAS_MODE == 1) v += bias[col];
        if (BIAS_MODE == 3) v += (col < 1024) ? bias[col] : bias2[col - 1024];
        const long long idx = cb0 + (long long)(by * 128 + row) * ldc + col;
        if (OUT_F32)
          ((float*)Cv)[idx] = v;
        else
          ((unsigned short*)Cv)[idx] = f2bf(v);
      }
      if (EPI == 1) {
        rps += __shfl_xor(rps, 1, 64);
        rps += __shfl_xor(rps, 2, 64);
        rps += __shfl_xor(rps, 4, 64);
        rps += __shfl_xor(rps, 8, 64);
        if (fr == 0) sredf[row * 2 + wn] = rps;
      }
    }
  if (EPI == 1) {
    __syncthreads();
    if (tid < 128) {
      const float s2 = sredf[tid * 2] + sredf[tid * 2 + 1];
      atomicAdd(Srow + (long long)bz * SEQ + by * 128 + tid, s2);
    }
  }
}

extern "C" void kernel_launch(void* const* d_in, const int* in_sizes, int n_in,
                              void* d_out, int out_size, void* d_ws,
                              size_t ws_size, hipStream_t stream) {
  (void)in_sizes; (void)n_in; (void)out_size; (void)ws_size;
  const float* x = (const float*)d_in[0];
  const float* Wq = (const float*)d_in[1];
  const float* bq = (const float*)d_in[2];
  const float* Wk = (const float*)d_in[3];
  const float* bk = (const float*)d_in[4];
  const float* Wv = (const float*)d_in[5];
  const float* bv = (const float*)d_in[6];
  const float* Wo = (const float*)d_in[7];
  const float* bo = (const float*)d_in[8];
  float* out = (float*)d_out;

  char* ws = (char*)d_ws;
  unsigned short* xbf  = (unsigned short*)(ws + 0);         // 16 MiB
  unsigned short* wqk  = (unsigned short*)(ws + 16777216);  // 4 MiB [2048][1024]
  unsigned short* wobf = (unsigned short*)(ws + 20971520);  // 2 MiB
  unsigned short* wvT  = (unsigned short*)(ws + 23068672);  // 2 MiB (Wv^T)
  unsigned short* wov  = (unsigned short*)(ws + 25165824);  // 2 MiB (Wo.Wv)
  float*          bpr  = (float*)        (ws + 27262976);   // 4 KiB (Wo.bv+bo)
  float*          Srow = (float*)        (ws + 28311552);   // 32 KiB rowsums
  unsigned short* VWoT = (unsigned short*)(ws + 33554432);  // 16 MiB [1024][8192]
  unsigned short* QKb  = (unsigned short*)(ws + 50331648);  // 32 MiB [8192][2048]
  unsigned short* P    = (unsigned short*)(ws + 83886080);  // 32 MiB [4][2048][2048]

  // casts & small precomputes
  cast_f32_to_bf16<<<4096, 256, 0, stream>>>(x, xbf, BS * HID);
  cast_f32_to_bf16<<<512, 256, 0, stream>>>(Wq, wqk, HID * HID);
  cast_f32_to_bf16<<<512, 256, 0, stream>>>(Wk, wqk + HID * HID, HID * HID);
  cast_f32_to_bf16<<<512, 256, 0, stream>>>(Wo, wobf, HID * HID);
  transpose_cast<<<dim3(32, 32), 256, 0, stream>>>(Wv, wvT);
  bias_fuse<<<256, 256, 0, stream>>>(Wo, bv, bo, bpr);
  hipMemsetAsync(Srow, 0, NB * SEQ * sizeof(float), stream);

  // WoWv[h,k] = sum_j Wo[h,j] Wv[j,k] = NT(Wo, Wv^T) : [1024,1024]
  gemm_p3<128, 0, 0, 0><<<dim3(8, 8, 1), 256, 0, stream>>>(
      wobf, wvT, wov, nullptr, nullptr, nullptr, HID, HID, HID, HID, 0, 0, 0,
      1.0f);
  // VWoT[h,s] = sum_k WoWv[h,k] x[s,k] = NT(WoWv, x) : [1024,8192]
  gemm_p3<64, 0, 0, 0><<<dim3(128, 8, 1), 256, 0, stream>>>(
      wov, xbf, VWoT, nullptr, nullptr, nullptr, HID, HID, HID, BS, 0, 0, 0,
      1.0f);
  // [Q|K] = x @ [Wq;Wk]^T + [bq;bk] : [8192,2048]
  gemm_p3<128, 0, 3, 0><<<dim3(16, 64, 1), 256, 0, stream>>>(
      xbf, wqk, QKb, bq, bk, nullptr, HID, HID, HID, 2048, 0, 0, 0, 1.0f);
  // P = exp(Q @ K^T / 32) per batch + rowsums : [4][2048][2048]
  gemm_p3<128, 0, 0, 1><<<dim3(16, 16, NB), 256, 0, stream>>>(
      QKb, QKb + 1024, P, nullptr, nullptr, Srow, HID, 2048, 2048, SEQ,
      (long long)SEQ * 2048, (long long)SEQ * 2048, (long long)SEQ * SEQ,
      0.03125f);
  // out = (P @ VWoT^T) / Srow + b' : [8192,1024] fp32 (k-window via bsB)
  gemm_p3<64, 1, 1, 2><<<dim3(16, 16, NB), 256, 0, stream>>>(
      P, VWoT, out, bpr, nullptr, Srow, SEQ, SEQ, BS, HID,
      (long long)SEQ * SEQ, (long long)SEQ, (long long)SEQ * HID, 1.0f);
}

// Round 8
// 245.042 us; speedup vs baseline: 1.0257x; 1.0257x over previous
//
#include <hip/hip_runtime.h>

#define HID 1024
#define SEQ 2048
#define NB 4
#define BS 8192  // NB*SEQ

typedef __attribute__((ext_vector_type(8))) short short8;
typedef __attribute__((ext_vector_type(8))) unsigned short ushort8;
typedef __attribute__((ext_vector_type(4))) float f32x4;

__device__ __forceinline__ float bf2f(unsigned short u) {
  unsigned int x = ((unsigned int)u) << 16;
  return __builtin_bit_cast(float, x);
}
__device__ __forceinline__ unsigned short f2bf(float f) {
  unsigned int x = __builtin_bit_cast(unsigned int, f);
  x = x + 0x7fffu + ((x >> 16) & 1u);
  return (unsigned short)(x >> 16);
}

#define GLOAD16(g, l)                                                          \
  __builtin_amdgcn_global_load_lds(                                            \
      (const __attribute__((address_space(1))) unsigned int*)(g),              \
      (__attribute__((address_space(3))) unsigned int*)(l), 16, 0, 0)

// ---------------- fp32 -> bf16 cast, 8 elems/thread ----------------
__global__ void cast_f32_to_bf16(const float* __restrict__ in,
                                 unsigned short* __restrict__ out, int n) {
  int i = (blockIdx.x * 256 + threadIdx.x) * 8;
  if (i >= n) return;
  f32x4 a = *(const f32x4*)(in + i);
  f32x4 b = *(const f32x4*)(in + i + 4);
  ushort8 o;
  o[0] = f2bf(a[0]); o[1] = f2bf(a[1]); o[2] = f2bf(a[2]); o[3] = f2bf(a[3]);
  o[4] = f2bf(b[0]); o[5] = f2bf(b[1]); o[6] = f2bf(b[2]); o[7] = f2bf(b[3]);
  *(ushort8*)(out + i) = o;
}

// ------------- 1024x1024 fp32 -> bf16 transposed cast -------------
__global__ __launch_bounds__(256) void transpose_cast(
    const float* __restrict__ in, unsigned short* __restrict__ out) {
  __shared__ float t[32][33];
  const int bx = blockIdx.x * 32, by = blockIdx.y * 32;
  const int tx = threadIdx.x & 31, ty = threadIdx.x >> 5;  // 32 x 8
#pragma unroll
  for (int i = 0; i < 4; ++i)
    t[ty + i * 8][tx] = in[(by + ty + i * 8) * 1024 + bx + tx];
  __syncthreads();
#pragma unroll
  for (int i = 0; i < 4; ++i)
    out[(bx + ty + i * 8) * 1024 + by + tx] = f2bf(t[tx][ty + i * 8]);
}

// ------------- b'[h] = bo[h] + sum_k Wo[h,k] * bv[k] -------------
__global__ __launch_bounds__(256) void bias_fuse(const float* __restrict__ Wo,
                                                 const float* __restrict__ bv,
                                                 const float* __restrict__ bo,
                                                 float* __restrict__ bp) {
  const int row = blockIdx.x * 4 + (threadIdx.x >> 6);
  const int lane = threadIdx.x & 63;
  float s = 0.f;
  for (int k = lane; k < 1024; k += 64) s += Wo[row * 1024 + k] * bv[k];
#pragma unroll
  for (int off = 32; off >= 1; off >>= 1) s += __shfl_xor(s, off, 64);
  if (lane == 0) bp[row] = s + bo[row];
}

// ================== 128 x BN TLP NT GEMM (BK=32, batched reads) ============
// C[m,n] = alpha * sum_k A[m,k]*B[n,k] (+bias). 256 thr = 4 waves (2x2),
// per-wave 64 x BN/2. Double-buffered LDS; 3 (BN=128) / 4 (BN=64) blocks/CU.
// KEY FIX (rule 18): all 8 fragment ds_reads are forced to ISSUE AND COMPLETE
// as a batch before the 16-MFMA cluster via
//   asm("s_waitcnt lgkmcnt(0)" ::: "memory") + sched_barrier(0).
// Without this the compiler re-materializes (VGPR 56!) into serial
// ds_read->mfma chains, exposing ~120cy LDS latency per read (the pinned
// 20% MfmaUtil of rounds 1-7).
// LDS XOR swizzle (0 conflicts, round-7-verified): phys 16B-slot =
// logical ^ (row bits 1-2), applied to the GLOBAL source column (gload_lds
// dest stays linear) and to every ds_read offset (rule 21 involution).
// BIAS_MODE: 0 none, 1 bias[col], 3 col<1024?bias:bias2.
// EPI: 0 plain, 1 exp(v)+rowsum->Srow atomics, 2 scale by 1/Srow.
template <int BN, int OUT_F32, int BIAS_MODE, int EPI>
__global__ __launch_bounds__(256, (BN == 128 ? 3 : 4)) void gemm_b(
    const unsigned short* __restrict__ A, const unsigned short* __restrict__ B,
    void* __restrict__ Cv, const float* __restrict__ bias,
    const float* __restrict__ bias2, float* __restrict__ Srow, int K, int lda,
    int ldb, int ldc, long long bsA, long long bsB, long long bsC,
    float alpha) {
  static_assert(BN == 128 || BN == 64, "BN");
  constexpr int NF = BN / 32;  // B frags per wave (4 or 2)

  __shared__ unsigned short lA[2][128 * 32];
  __shared__ unsigned short lB[2][BN * 32];

  const int tid = threadIdx.x;
  const int lane = tid & 63, wid = tid >> 6;
  const int fr = lane & 15, fq = lane >> 4;
  const int wm = wid >> 1, wn = wid & 1;

  // XCD-aware chunked swizzle on flattened (y,x); all grids have nwg%8==0.
  const int nx = gridDim.x;
  const int nwg = nx * gridDim.y;
  int f = blockIdx.y * nx + blockIdx.x;
  f = (f & 7) * (nwg >> 3) + (f >> 3);
  const int bx = f % nx, by = f / nx;
  const int bz = blockIdx.z;

  const unsigned short* Ag = A + bz * bsA + (long long)by * 128 * lda;
  const unsigned short* Bg = B + bz * bsB + (long long)bx * BN * ldb;
  const int NT = K >> 5;  // always even here (K multiple of 64)

  // Staging: LDS dest linear (wave-uniform base + lane*16B). Global source
  // column pre-swizzled: phys slot (tid&3) holds logical slot
  // (tid&3)^((row>>1)&3), row = tid>>2.  (0 conflicts, round-7.)
  const int srow = tid >> 2;
  const int scol = 8 * ((tid & 3) ^ ((tid >> 3) & 3));
  const int lbase = wid * 512;  // ushorts, wave-uniform

  auto stageA = [&](int t, int b) {
    unsigned short* d = &lA[b][lbase];
    GLOAD16(Ag + (long long)srow * lda + t * 32 + scol, d);
    GLOAD16(Ag + (long long)(64 + srow) * lda + t * 32 + scol, d + 2048);
  };
  auto stageB = [&](int t, int b) {
    unsigned short* d = &lB[b][lbase];
    GLOAD16(Bg + (long long)srow * ldb + t * 32 + scol, d);
    if (BN == 128)
      GLOAD16(Bg + (long long)(64 + srow) * ldb + t * 32 + scol, d + 2048);
  };

  // ds_read offsets: XOR the 16B-slot with row bits 1-2 (= fr bits 1-2).
  const int xm = ((fr >> 1) & 3) << 3;  // ushort-unit mask (bits 3-4)

  f32x4 acc[4][NF] = {};

  auto compute = [&](const unsigned short* pa, const unsigned short* pb) {
    short8 av[4], bw[NF];
#pragma unroll
    for (int i = 0; i < 4; ++i)
      av[i] = *(const short8*)(pa +
                               (((wm * 64 + i * 16 + fr) * 32 + fq * 8) ^ xm));
#pragma unroll
    for (int n = 0; n < NF; ++n)
      bw[n] = *(const short8*)(pb + (((wn * (BN / 2) + n * 16 + fr) * 32 +
                                      fq * 8) ^ xm));
    // Force the batch: loads cannot sink past the clobber; MFMAs cannot
    // hoist past the sched_barrier (rule 18). Keeps all 8 frags live.
    asm volatile("s_waitcnt lgkmcnt(0)" ::: "memory");
    __builtin_amdgcn_sched_barrier(0);
#pragma unroll
    for (int i = 0; i < 4; ++i)
#pragma unroll
      for (int n = 0; n < NF; ++n)
        acc[i][n] = __builtin_amdgcn_mfma_f32_16x16x32_bf16(av[i], bw[n],
                                                            acc[i][n], 0, 0, 0);
  };

  stageA(0, 0);
  stageB(0, 0);
  __syncthreads();

  for (int t = 0; t < NT; t += 2) {
    // even: compute buf0 (tile t), prefetch tile t+1 -> buf1
    stageA(t + 1, 1);
    stageB(t + 1, 1);
    compute(lA[0], lB[0]);
    __syncthreads();  // drains vm (publishes buf1) + closes buf0 reads
    // odd: compute buf1 (tile t+1), prefetch tile t+2 -> buf0
    if (t + 2 < NT) {
      stageA(t + 2, 0);
      stageB(t + 2, 0);
    }
    compute(lA[1], lB[1]);
    __syncthreads();
  }

  // Epilogue. C/D frag layout: col = 16*frag + fr, row = fq*4 + j.
  const long long cb0 = (long long)bz * bsC;
  float* sredf = (float*)lA;  // [128][2] row-sum scratch (EPI==1)
#pragma unroll
  for (int i = 0; i < 4; ++i)
#pragma unroll
    for (int j = 0; j < 4; ++j) {
      const int row = wm * 64 + i * 16 + fq * 4 + j;
      float inv = 1.0f;
      if (EPI == 2) inv = 1.0f / Srow[(long long)bz * SEQ + by * 128 + row];
      float rps = 0.0f;
#pragma unroll
      for (int n = 0; n < NF; ++n) {
        const int col = bx * BN + wn * (BN / 2) + n * 16 + fr;
        float v = acc[i][n][j] * alpha;
        if (EPI == 1) { v = __expf(v); rps += v; }
        if (EPI == 2) v *= inv;
        if (BIAS_MODE == 1) v += bias[col];
        if (BIAS_MODE == 3) v += (col < 1024) ? bias[col] : bias2[col - 1024];
        const long long idx = cb0 + (long long)(by * 128 + row) * ldc + col;
        if (OUT_F32)
          ((float*)Cv)[idx] = v;
        else
          ((unsigned short*)Cv)[idx] = f2bf(v);
      }
      if (EPI == 1) {
        rps += __shfl_xor(rps, 1, 64);
        rps += __shfl_xor(rps, 2, 64);
        rps += __shfl_xor(rps, 4, 64);
        rps += __shfl_xor(rps, 8, 64);
        if (fr == 0) sredf[row * 2 + wn] = rps;
      }
    }
  if (EPI == 1) {
    __syncthreads();
    if (tid < 128) {
      const float s2 = sredf[tid * 2] + sredf[tid * 2 + 1];
      atomicAdd(Srow + (long long)bz * SEQ + by * 128 + tid, s2);
    }
  }
}

extern "C" void kernel_launch(void* const* d_in, const int* in_sizes, int n_in,
                              void* d_out, int out_size, void* d_ws,
                              size_t ws_size, hipStream_t stream) {
  (void)in_sizes; (void)n_in; (void)out_size; (void)ws_size;
  const float* x = (const float*)d_in[0];
  const float* Wq = (const float*)d_in[1];
  const float* bq = (const float*)d_in[2];
  const float* Wk = (const float*)d_in[3];
  const float* bk = (const float*)d_in[4];
  const float* Wv = (const float*)d_in[5];
  const float* bv = (const float*)d_in[6];
  const float* Wo = (const float*)d_in[7];
  const float* bo = (const float*)d_in[8];
  float* out = (float*)d_out;

  char* ws = (char*)d_ws;
  unsigned short* xbf  = (unsigned short*)(ws + 0);         // 16 MiB
  unsigned short* wqk  = (unsigned short*)(ws + 16777216);  // 4 MiB [2048][1024]
  unsigned short* wobf = (unsigned short*)(ws + 20971520);  // 2 MiB
  unsigned short* wvT  = (unsigned short*)(ws + 23068672);  // 2 MiB (Wv^T)
  unsigned short* wov  = (unsigned short*)(ws + 25165824);  // 2 MiB (Wo.Wv)
  float*          bpr  = (float*)        (ws + 27262976);   // 4 KiB (Wo.bv+bo)
  float*          Srow = (float*)        (ws + 28311552);   // 32 KiB rowsums
  unsigned short* VWoT = (unsigned short*)(ws + 33554432);  // 16 MiB [1024][8192]
  unsigned short* QKb  = (unsigned short*)(ws + 50331648);  // 32 MiB [8192][2048]
  unsigned short* P    = (unsigned short*)(ws + 83886080);  // 32 MiB [4][2048][2048]

  // casts & small precomputes
  cast_f32_to_bf16<<<4096, 256, 0, stream>>>(x, xbf, BS * HID);
  cast_f32_to_bf16<<<512, 256, 0, stream>>>(Wq, wqk, HID * HID);
  cast_f32_to_bf16<<<512, 256, 0, stream>>>(Wk, wqk + HID * HID, HID * HID);
  cast_f32_to_bf16<<<512, 256, 0, stream>>>(Wo, wobf, HID * HID);
  transpose_cast<<<dim3(32, 32), 256, 0, stream>>>(Wv, wvT);
  bias_fuse<<<256, 256, 0, stream>>>(Wo, bv, bo, bpr);
  hipMemsetAsync(Srow, 0, NB * SEQ * sizeof(float), stream);

  // WoWv[h,k] = sum_j Wo[h,j] Wv[j,k] = NT(Wo, Wv^T) : [1024,1024]
  gemm_b<128, 0, 0, 0><<<dim3(8, 8, 1), 256, 0, stream>>>(
      wobf, wvT, wov, nullptr, nullptr, nullptr, HID, HID, HID, HID, 0, 0, 0,
      1.0f);
  // VWoT[h,s] = sum_k WoWv[h,k] x[s,k] = NT(WoWv, x) : [1024,8192]
  gemm_b<64, 0, 0, 0><<<dim3(128, 8, 1), 256, 0, stream>>>(
      wov, xbf, VWoT, nullptr, nullptr, nullptr, HID, HID, HID, BS, 0, 0, 0,
      1.0f);
  // [Q|K] = x @ [Wq;Wk]^T + [bq;bk] : [8192,2048]
  gemm_b<128, 0, 3, 0><<<dim3(16, 64, 1), 256, 0, stream>>>(
      xbf, wqk, QKb, bq, bk, nullptr, HID, HID, HID, 2048, 0, 0, 0, 1.0f);
  // P = exp(Q @ K^T / 32) per batch + rowsums : [4][2048][2048]
  gemm_b<128, 0, 0, 1><<<dim3(16, 16, NB), 256, 0, stream>>>(
      QKb, QKb + 1024, P, nullptr, nullptr, Srow, HID, 2048, 2048, SEQ,
      (long long)SEQ * 2048, (long long)SEQ * 2048, (long long)SEQ * SEQ,
      0.03125f);
  // out = (P @ VWoT^T) / Srow + b' : [8192,1024] fp32 (k-window via bsB)
  gemm_b<64, 1, 1, 2><<<dim3(16, 16, NB), 256, 0, stream>>>(
      P, VWoT, out, bpr, nullptr, Srow, SEQ, SEQ, BS, HID,
      (long long)SEQ * SEQ, (long long)SEQ, (long long)SEQ * HID, 1.0f);
}

// Round 9
// 237.551 us; speedup vs baseline: 1.0580x; 1.0315x over previous
//
#include <hip/hip_runtime.h>

#define HID 1024
#define SEQ 2048
#define NB 4
#define BS 8192  // NB*SEQ

typedef __attribute__((ext_vector_type(8))) short short8;
typedef __attribute__((ext_vector_type(8))) unsigned short ushort8;
typedef __attribute__((ext_vector_type(4))) float f32x4;

__device__ __forceinline__ float bf2f(unsigned short u) {
  unsigned int x = ((unsigned int)u) << 16;
  return __builtin_bit_cast(float, x);
}
__device__ __forceinline__ unsigned short f2bf(float f) {
  unsigned int x = __builtin_bit_cast(unsigned int, f);
  x = x + 0x7fffu + ((x >> 16) & 1u);
  return (unsigned short)(x >> 16);
}

#define GLOAD16(g, l)                                                          \
  __builtin_amdgcn_global_load_lds(                                            \
      (const __attribute__((address_space(1))) unsigned int*)(g),              \
      (__attribute__((address_space(3))) unsigned int*)(l), 16, 0, 0)

// ---------------- fp32 -> bf16 cast, 8 elems/thread ----------------
__global__ void cast_f32_to_bf16(const float* __restrict__ in,
                                 unsigned short* __restrict__ out, int n) {
  int i = (blockIdx.x * 256 + threadIdx.x) * 8;
  if (i >= n) return;
  f32x4 a = *(const f32x4*)(in + i);
  f32x4 b = *(const f32x4*)(in + i + 4);
  ushort8 o;
  o[0] = f2bf(a[0]); o[1] = f2bf(a[1]); o[2] = f2bf(a[2]); o[3] = f2bf(a[3]);
  o[4] = f2bf(b[0]); o[5] = f2bf(b[1]); o[6] = f2bf(b[2]); o[7] = f2bf(b[3]);
  *(ushort8*)(out + i) = o;
}

// ------------- 1024x1024 fp32 -> bf16 transposed cast -------------
__global__ __launch_bounds__(256) void transpose_cast(
    const float* __restrict__ in, unsigned short* __restrict__ out) {
  __shared__ float t[32][33];
  const int bx = blockIdx.x * 32, by = blockIdx.y * 32;
  const int tx = threadIdx.x & 31, ty = threadIdx.x >> 5;  // 32 x 8
#pragma unroll
  for (int i = 0; i < 4; ++i)
    t[ty + i * 8][tx] = in[(by + ty + i * 8) * 1024 + bx + tx];
  __syncthreads();
#pragma unroll
  for (int i = 0; i < 4; ++i)
    out[(bx + ty + i * 8) * 1024 + by + tx] = f2bf(t[tx][ty + i * 8]);
}

// ------------- b'[h] = bo[h] + sum_k Wo[h,k] * bv[k] -------------
__global__ __launch_bounds__(256) void bias_fuse(const float* __restrict__ Wo,
                                                 const float* __restrict__ bv,
                                                 const float* __restrict__ bo,
                                                 float* __restrict__ bp) {
  const int row = blockIdx.x * 4 + (threadIdx.x >> 6);
  const int lane = threadIdx.x & 63;
  float s = 0.f;
  for (int k = lane; k < 1024; k += 64) s += Wo[row * 1024 + k] * bv[k];
#pragma unroll
  for (int off = 32; off >= 1; off >>= 1) s += __shfl_xor(s, off, 64);
  if (lane == 0) bp[row] = s + bo[row];
}

// ============== 256x128 NT GEMM, 128x64 per wave (BK=32) ===================
// C[m,n] = alpha * sum_k A[m,k]*B[n,k] (+bias). 256 thr = 4 waves (2Mx2N),
// per-wave output 128x64 read-once: 12 ds_read_b128 -> 32 MFMAs
// = 384 B/MFMA LDS traffic (vs 512 at 64x64/wave: the LDS-read-throughput
// bound that pinned rounds 1-8 at ~20% MfmaUtil).
// Double-buffered 48KB LDS, 2 blocks/CU (VGPR ~200 -> launch_bounds(256,2)).
// Proven pieces kept: 0-conflict XOR swizzle (phys 16B-slot = logical ^
// row bits 1-2; applied to global source col + ds_read offsets, rule 21),
// batched lgkmcnt(0)+sched_barrier (rule 18), XCD block swizzle.
// BIAS_MODE: 0 none, 1 bias[col], 3 col<1024?bias:bias2.
// EPI: 0 plain, 1 exp(v)+rowsum->Srow atomics, 2 scale by 1/Srow.
template <int OUT_F32, int BIAS_MODE, int EPI>
__global__ __launch_bounds__(256, 2) void gemm_w(
    const unsigned short* __restrict__ A, const unsigned short* __restrict__ B,
    void* __restrict__ Cv, const float* __restrict__ bias,
    const float* __restrict__ bias2, float* __restrict__ Srow, int K, int lda,
    int ldb, int ldc, long long bsA, long long bsB, long long bsC,
    float alpha) {
  __shared__ unsigned short lA[2][256 * 32];  // 32 KB
  __shared__ unsigned short lB[2][128 * 32];  // 16 KB

  const int tid = threadIdx.x;
  const int lane = tid & 63, wid = tid >> 6;
  const int fr = lane & 15, fq = lane >> 4;
  const int wm = wid >> 1, wn = wid & 1;  // 2M x 2N waves

  // XCD-aware chunked swizzle on flattened (y,x); all grids have nwg%8==0.
  const int nx = gridDim.x;
  const int nwg = nx * gridDim.y;
  int f = blockIdx.y * nx + blockIdx.x;
  f = (f & 7) * (nwg >> 3) + (f >> 3);
  const int bx = f % nx, by = f / nx;
  const int bz = blockIdx.z;

  const unsigned short* Ag = A + bz * bsA + (long long)by * 256 * lda;
  const unsigned short* Bg = B + bz * bsB + (long long)bx * 128 * ldb;
  const int NT = K >> 5;  // K multiple of 64 -> NT even

  // Staging: LDS dest linear (wave-uniform base + lane*16B). Global source
  // column pre-swizzled: phys slot (tid&3) holds logical slot
  // (tid&3)^((row>>1)&3). srow = wid*16 + lane/4 matches dest lane order.
  const int srow = tid >> 2;                           // in [0,64) per chunk
  const int scol = 8 * ((tid & 3) ^ ((tid >> 3) & 3)); // swizzled 16B slot
  const int lbase = wid * 512;  // ushorts, wave-uniform

  auto stageA = [&](int t, int b) {
#pragma unroll
    for (int c = 0; c < 4; ++c)
      GLOAD16(Ag + (long long)(c * 64 + srow) * lda + t * 32 + scol,
              &lA[b][c * 2048 + lbase]);
  };
  auto stageB = [&](int t, int b) {
#pragma unroll
    for (int c = 0; c < 2; ++c)
      GLOAD16(Bg + (long long)(c * 64 + srow) * ldb + t * 32 + scol,
              &lB[b][c * 2048 + lbase]);
  };

  // ds_read offsets: XOR the 16B-slot with row bits 1-2 (= fr bits 1-2).
  const int xm = ((fr >> 1) & 3) << 3;  // ushort-unit mask (bits 3-4)

  f32x4 acc[8][4] = {};

  auto compute = [&](const unsigned short* pa, const unsigned short* pb) {
    short8 av[8], bw[4];
#pragma unroll
    for (int i = 0; i < 8; ++i)
      av[i] = *(const short8*)(pa +
                               (((wm * 128 + i * 16 + fr) * 32 + fq * 8) ^ xm));
#pragma unroll
    for (int n = 0; n < 4; ++n)
      bw[n] = *(const short8*)(pb +
                               (((wn * 64 + n * 16 + fr) * 32 + fq * 8) ^ xm));
    // Batch: loads can't sink past the clobber; MFMAs can't hoist (rule 18).
    asm volatile("s_waitcnt lgkmcnt(0)" ::: "memory");
    __builtin_amdgcn_sched_barrier(0);
#pragma unroll
    for (int i = 0; i < 8; ++i)
#pragma unroll
      for (int n = 0; n < 4; ++n)
        acc[i][n] = __builtin_amdgcn_mfma_f32_16x16x32_bf16(av[i], bw[n],
                                                            acc[i][n], 0, 0, 0);
  };

  stageA(0, 0);
  stageB(0, 0);
  __syncthreads();

  for (int t = 0; t < NT; t += 2) {
    // even: compute buf0 (tile t), prefetch tile t+1 -> buf1
    stageA(t + 1, 1);
    stageB(t + 1, 1);
    compute(lA[0], lB[0]);
    __syncthreads();  // drains vm (publishes buf1) + closes buf0 reads
    // odd: compute buf1 (tile t+1), prefetch tile t+2 -> buf0
    if (t + 2 < NT) {
      stageA(t + 2, 0);
      stageB(t + 2, 0);
    }
    compute(lA[1], lB[1]);
    __syncthreads();
  }

  // Epilogue. C/D frag layout: col = 16*frag + fr, row = fq*4 + j.
  const long long cb0 = (long long)bz * bsC;
  float* sredf = (float*)lA;  // [256][2] row-sum scratch (EPI==1)
#pragma unroll
  for (int i = 0; i < 8; ++i)
#pragma unroll
    for (int j = 0; j < 4; ++j) {
      const int row = wm * 128 + i * 16 + fq * 4 + j;
      float inv = 1.0f;
      if (EPI == 2) inv = 1.0f / Srow[(long long)bz * SEQ + by * 256 + row];
      float rps = 0.0f;
#pragma unroll
      for (int n = 0; n < 4; ++n) {
        const int col = bx * 128 + wn * 64 + n * 16 + fr;
        float v = acc[i][n][j] * alpha;
        if (EPI == 1) { v = __expf(v); rps += v; }
        if (EPI == 2) v *= inv;
        if (BIAS_MODE == 1) v += bias[col];
        if (BIAS_MODE == 3) v += (col < 1024) ? bias[col] : bias2[col - 1024];
        const long long idx = cb0 + (long long)(by * 256 + row) * ldc + col;
        if (OUT_F32)
          ((float*)Cv)[idx] = v;
        else
          ((unsigned short*)Cv)[idx] = f2bf(v);
      }
      if (EPI == 1) {
        rps += __shfl_xor(rps, 1, 64);
        rps += __shfl_xor(rps, 2, 64);
        rps += __shfl_xor(rps, 4, 64);
        rps += __shfl_xor(rps, 8, 64);
        if (fr == 0) sredf[row * 2 + wn] = rps;
      }
    }
  if (EPI == 1) {
    __syncthreads();
    if (tid < 256) {
      const float s2 = sredf[tid * 2] + sredf[tid * 2 + 1];
      atomicAdd(Srow + (long long)bz * SEQ + by * 256 + tid, s2);
    }
  }
}

extern "C" void kernel_launch(void* const* d_in, const int* in_sizes, int n_in,
                              void* d_out, int out_size, void* d_ws,
                              size_t ws_size, hipStream_t stream) {
  (void)in_sizes; (void)n_in; (void)out_size; (void)ws_size;
  const float* x = (const float*)d_in[0];
  const float* Wq = (const float*)d_in[1];
  const float* bq = (const float*)d_in[2];
  const float* Wk = (const float*)d_in[3];
  const float* bk = (const float*)d_in[4];
  const float* Wv = (const float*)d_in[5];
  const float* bv = (const float*)d_in[6];
  const float* Wo = (const float*)d_in[7];
  const float* bo = (const float*)d_in[8];
  float* out = (float*)d_out;

  char* ws = (char*)d_ws;
  unsigned short* xbf  = (unsigned short*)(ws + 0);         // 16 MiB
  unsigned short* wqk  = (unsigned short*)(ws + 16777216);  // 4 MiB [2048][1024]
  unsigned short* wobf = (unsigned short*)(ws + 20971520);  // 2 MiB
  unsigned short* wvT  = (unsigned short*)(ws + 23068672);  // 2 MiB (Wv^T)
  unsigned short* wov  = (unsigned short*)(ws + 25165824);  // 2 MiB (Wo.Wv)
  float*          bpr  = (float*)        (ws + 27262976);   // 4 KiB (Wo.bv+bo)
  float*          Srow = (float*)        (ws + 28311552);   // 32 KiB rowsums
  unsigned short* VWoT = (unsigned short*)(ws + 33554432);  // 16 MiB [1024][8192]
  unsigned short* QKb  = (unsigned short*)(ws + 50331648);  // 32 MiB [8192][2048]
  unsigned short* P    = (unsigned short*)(ws + 83886080);  // 32 MiB [4][2048][2048]

  // casts & small precomputes
  cast_f32_to_bf16<<<4096, 256, 0, stream>>>(x, xbf, BS * HID);
  cast_f32_to_bf16<<<512, 256, 0, stream>>>(Wq, wqk, HID * HID);
  cast_f32_to_bf16<<<512, 256, 0, stream>>>(Wk, wqk + HID * HID, HID * HID);
  cast_f32_to_bf16<<<512, 256, 0, stream>>>(Wo, wobf, HID * HID);
  transpose_cast<<<dim3(32, 32), 256, 0, stream>>>(Wv, wvT);
  bias_fuse<<<256, 256, 0, stream>>>(Wo, bv, bo, bpr);
  hipMemsetAsync(Srow, 0, NB * SEQ * sizeof(float), stream);

  // WoWv[h,k] = sum_j Wo[h,j] Wv[j,k] = NT(Wo, Wv^T) : [1024,1024]
  gemm_w<0, 0, 0><<<dim3(8, 4, 1), 256, 0, stream>>>(
      wobf, wvT, wov, nullptr, nullptr, nullptr, HID, HID, HID, HID, 0, 0, 0,
      1.0f);
  // VWoT[h,s] = sum_k WoWv[h,k] x[s,k] = NT(WoWv, x) : [1024,8192]
  gemm_w<0, 0, 0><<<dim3(64, 4, 1), 256, 0, stream>>>(
      wov, xbf, VWoT, nullptr, nullptr, nullptr, HID, HID, HID, BS, 0, 0, 0,
      1.0f);
  // [Q|K] = x @ [Wq;Wk]^T + [bq;bk] : [8192,2048]
  gemm_w<0, 3, 0><<<dim3(16, 32, 1), 256, 0, stream>>>(
      xbf, wqk, QKb, bq, bk, nullptr, HID, HID, HID, 2048, 0, 0, 0, 1.0f);
  // P = exp(Q @ K^T / 32) per batch + rowsums : [4][2048][2048]
  gemm_w<0, 0, 1><<<dim3(16, 8, NB), 256, 0, stream>>>(
      QKb, QKb + 1024, P, nullptr, nullptr, Srow, HID, 2048, 2048, SEQ,
      (long long)SEQ * 2048, (long long)SEQ * 2048, (long long)SEQ * SEQ,
      0.03125f);
  // out = (P @ VWoT^T) / Srow + b' : [8192,1024] fp32 (k-window via bsB)
  gemm_w<1, 1, 2><<<dim3(8, 8, NB), 256, 0, stream>>>(
      P, VWoT, out, bpr, nullptr, Srow, SEQ, SEQ, BS, HID,
      (long long)SEQ * SEQ, (long long)SEQ, (long long)SEQ * HID, 1.0f);
}